// Round 1
// baseline (991.692 us; speedup 1.0000x reference)
//
#include <hip/hip_runtime.h>

#define TPB 128

// fast tanh/sigmoid via hardware exp; exact at +-inf (exp->inf => rcp->0)
__device__ __forceinline__ float ftanh(float x){
    float t = __expf(2.0f * x);
    return 1.0f - __fdividef(2.0f, t + 1.0f);
}
__device__ __forceinline__ float fsigm(float x){
    return __fdividef(1.0f, 1.0f + __expf(-x));
}

__device__ __forceinline__ void initb(const float* __restrict__ b, float (&acc)[64]){
    #pragma unroll
    for (int j = 0; j < 64; ++j) acc[j] = b[j];
}

// acc[j] += sum_k x[k] * W[k*64+j]   (x static in regs, W wave-uniform -> s_load)
template<int IN>
__device__ __forceinline__ void layer_small(const float* __restrict__ W,
                                            const float (&x)[IN], float (&acc)[64]){
    #pragma unroll
    for (int k = 0; k < IN; ++k){
        const float xv = x[k];
        const float* __restrict__ Wr = W + k * 64;
        #pragma unroll
        for (int j = 0; j < 64; ++j) acc[j] = __fmaf_rn(xv, Wr[j], acc[j]);
    }
}

// acc[j] += sum_k H[k][tid] * W[k*64+j], H read 4-at-a-time via ds_read_b128
__device__ __forceinline__ void layer64(const float* __restrict__ W,
                                        float (&acc)[64],
                                        float (*Hs)[TPB][4], int tid){
    #pragma unroll 2
    for (int kb = 0; kb < 16; ++kb){
        const float4 h4 = *(const float4*)(&Hs[kb][tid][0]);
        const float* __restrict__ Wr = W + kb * 256;
        #pragma unroll
        for (int j = 0; j < 64; ++j) acc[j] = __fmaf_rn(h4.x, Wr[j],       acc[j]);
        #pragma unroll
        for (int j = 0; j < 64; ++j) acc[j] = __fmaf_rn(h4.y, Wr[64 + j],  acc[j]);
        #pragma unroll
        for (int j = 0; j < 64; ++j) acc[j] = __fmaf_rn(h4.z, Wr[128 + j], acc[j]);
        #pragma unroll
        for (int j = 0; j < 64; ++j) acc[j] = __fmaf_rn(h4.w, Wr[192 + j], acc[j]);
    }
}

__device__ __forceinline__ void storeH(const float (&v)[64], float (*Hs)[TPB][4], int tid){
    #pragma unroll
    for (int jb = 0; jb < 16; ++jb){
        float4 t;
        t.x = v[4*jb]; t.y = v[4*jb+1]; t.z = v[4*jb+2]; t.w = v[4*jb+3];
        *(float4*)(&Hs[jb][tid][0]) = t;
    }
}

__global__ __launch_bounds__(TPB, 2)
void net_kernel(const float* __restrict__ states, const float* __restrict__ action,
                const float* __restrict__ b_type, const float* __restrict__ table,
                const float* __restrict__ W1,  const float* __restrict__ b1,
                const float* __restrict__ W1b, const float* __restrict__ b1b,
                const float* __restrict__ W1c, const float* __restrict__ b1c,
                const float* __restrict__ W2a, const float* __restrict__ b2a,
                const float* __restrict__ W2b, const float* __restrict__ b2b,
                const float* __restrict__ Ta1, const float* __restrict__ ta1,
                const float* __restrict__ Ta2, const float* __restrict__ ta2,
                const float* __restrict__ Tb1, const float* __restrict__ tb1,
                const float* __restrict__ Tb2, const float* __restrict__ tb2,
                float* __restrict__ out, int Btot)
{
    // per-thread hidden vector, [kb][tid][4] so dynamic-k access is ds_read_b128,
    // lane-consecutive addresses -> conflict-free. 16*128*4*4B = 32 KB.
    __shared__ float Hs[16][TPB][4];
    const int tid = threadIdx.x;
    const int e = blockIdx.x * TPB + tid;
    if (e >= Btot) return;

    float a8[8];
    {
        const float4 a0 = *(const float4*)(action + e * 8);
        const float4 a1 = *(const float4*)(action + e * 8 + 4);
        a8[0]=a0.x; a8[1]=a0.y; a8[2]=a0.z; a8[3]=a0.w;
        a8[4]=a1.x; a8[5]=a1.y; a8[6]=a1.z; a8[7]=a1.w;
    }

    // ---- gate1 = tanh(tanh(b_type@Ta1+ta1)@Ta2+ta2) ----
    float g[64];
    {
        float x5[5];
        const float* bp = b_type + e * 5;
        #pragma unroll
        for (int k = 0; k < 5; ++k) x5[k] = bp[k];
        float acc[64];
        initb(ta1, acc);
        layer_small<5>(Ta1, x5, acc);
        #pragma unroll
        for (int j = 0; j < 64; ++j) acc[j] = ftanh(acc[j]);
        storeH(acc, Hs, tid);
        initb(ta2, g);
        layer64(Ta2, g, Hs, tid);
        #pragma unroll
        for (int j = 0; j < 64; ++j) g[j] = ftanh(g[j]);
    }

    float out8[8];
    #pragma unroll
    for (int i = 0; i < 8; ++i) out8[i] = a8[i];   // residual: out = action + ...

    float T[64];
    #pragma unroll 1
    for (int r = 0; r < 4; ++r){
        const bool ht = (r < 3);

        // tg = type_mlp(states[...,13:18]) for rows 0..2
        if (ht){
            const float* sp = states + e * 54 + r * 18;
            float x5[5];
            #pragma unroll
            for (int k = 0; k < 5; ++k) x5[k] = sp[13 + k];
            float acc[64];
            initb(tb1, acc);
            layer_small<5>(Tb1, x5, acc);
            #pragma unroll
            for (int j = 0; j < 64; ++j) acc[j] = ftanh(acc[j]);
            storeH(acc, Hs, tid);
            initb(tb2, T);
            layer64(Tb2, T, Hs, tid);
            #pragma unroll
            for (int j = 0; j < 64; ++j) T[j] = ftanh(T[j]);
        }

        // x = [rel_r (8), st_r or table (6)]
        float x14[14]; float st0 = 0.0f;
        #pragma unroll
        for (int k = 0; k < 8; ++k) x14[k] = a8[k];
        if (ht){
            const float* sp = states + e * 54 + r * 18;
            x14[0] -= sp[0];
            x14[1] -= sp[1];
            #pragma unroll
            for (int k = 0; k < 6; ++k) x14[8 + k] = sp[3 + k];
            st0 = x14[8];
        } else {
            const float* tp = table + e * 6;
            #pragma unroll
            for (int k = 0; k < 6; ++k) x14[8 + k] = tp[k];
        }

        // stack(): h=tanh(x@W1+b1); h=tanh(h@W1b+b1b)*gate1; h=tanh(h@W1c+b1c)
        float acc[64];
        initb(b1, acc);
        layer_small<14>(W1, x14, acc);
        #pragma unroll
        for (int j = 0; j < 64; ++j) acc[j] = ftanh(acc[j]);
        storeH(acc, Hs, tid);

        initb(b1b, acc);
        layer64(W1b, acc, Hs, tid);
        #pragma unroll
        for (int j = 0; j < 64; ++j) acc[j] = ftanh(acc[j]) * g[j];
        storeH(acc, Hs, tid);

        initb(b1c, acc);
        layer64(W1c, acc, Hs, tid);
        #pragma unroll
        for (int j = 0; j < 64; ++j) acc[j] = ftanh(acc[j]);
        if (ht){
            #pragma unroll
            for (int j = 0; j < 64; ++j) acc[j] *= T[j];
        }

        // head: w = sigmoid(h@W2b+b2b) (masked), v = h@W2a+b2a; out += w*v
        float wv = b2b[0];
        float v8[8];
        #pragma unroll
        for (int i = 0; i < 8; ++i) v8[i] = b2a[i];
        #pragma unroll
        for (int j = 0; j < 64; ++j){
            const float hj = acc[j];
            wv = __fmaf_rn(hj, W2b[j], wv);
            const float* __restrict__ wr = W2a + j * 8;
            #pragma unroll
            for (int i = 0; i < 8; ++i) v8[i] = __fmaf_rn(hj, wr[i], v8[i]);
        }
        float w = fsigm(wv);
        if (ht && st0 == -1.0f) w = 0.0f;
        #pragma unroll
        for (int i = 0; i < 8; ++i) out8[i] = __fmaf_rn(w, v8[i], out8[i]);
    }

    float* op = out + e * 8;
    *(float4*)(op)     = make_float4(out8[0], out8[1], out8[2], out8[3]);
    *(float4*)(op + 4) = make_float4(out8[4], out8[5], out8[6], out8[7]);
}

extern "C" void kernel_launch(void* const* d_in, const int* in_sizes, int n_in,
                              void* d_out, int out_size, void* d_ws, size_t ws_size,
                              hipStream_t stream)
{
    const float* states = (const float*)d_in[0];
    const float* action = (const float*)d_in[1];
    const float* b_type = (const float*)d_in[2];
    const float* table  = (const float*)d_in[3];
    const float* W1  = (const float*)d_in[4];
    const float* b1  = (const float*)d_in[5];
    const float* W1b = (const float*)d_in[6];
    const float* b1b = (const float*)d_in[7];
    const float* W1c = (const float*)d_in[8];
    const float* b1c = (const float*)d_in[9];
    const float* W2a = (const float*)d_in[10];
    const float* b2a = (const float*)d_in[11];
    const float* W2b = (const float*)d_in[12];
    const float* b2b = (const float*)d_in[13];
    const float* Ta1 = (const float*)d_in[14];
    const float* ta1 = (const float*)d_in[15];
    const float* Ta2 = (const float*)d_in[16];
    const float* ta2 = (const float*)d_in[17];
    const float* Tb1 = (const float*)d_in[18];
    const float* tb1 = (const float*)d_in[19];
    const float* Tb2 = (const float*)d_in[20];
    const float* tb2 = (const float*)d_in[21];
    float* out = (float*)d_out;

    const int Btot = in_sizes[1] / 8;   // action is (B, 8)
    const int grid = (Btot + TPB - 1) / TPB;
    net_kernel<<<dim3(grid), dim3(TPB), 0, stream>>>(
        states, action, b_type, table,
        W1, b1, W1b, b1b, W1c, b1c, W2a, b2a, W2b, b2b,
        Ta1, ta1, Ta2, ta2, Tb1, tb1, Tb2, tb2,
        out, Btot);
}

// Round 2
// 270.167 us; speedup vs baseline: 3.6707x; 3.6707x over previous
//
#include <hip/hip_runtime.h>

typedef unsigned int  uint;
typedef unsigned short u16;
typedef __attribute__((ext_vector_type(8))) short bf16x8;   // 8 bf16 in 4 VGPRs
typedef __attribute__((ext_vector_type(4))) float f32x4;

// ---- LDS weight-fragment offsets (bf16 units) ----
#define OF_W1B   0
#define OF_W1C   4096
#define OF_TA2   8192
#define OF_TB2   12288
#define OF_W1    16384
#define OF_TA1   18432
#define OF_TB1   20480
#define OF_W2AB  22528
#define WTOT     23552
// ---- bias offsets (f32 units) ----
#define BTA1 0
#define BTA2 64
#define BTB1 128
#define BTB2 192
#define BB1  256
#define BB1B 320
#define BB1C 384
#define BH   448   // [0..7]=b2a, [8]=b2b, rest 0

__device__ __forceinline__ float ftanh(float x){
    float t = __expf(2.0f * x);                 // v_mul + v_exp
    return 1.0f - __fdividef(2.0f, t + 1.0f);   // v_add + v_rcp + v_fma
}
__device__ __forceinline__ float fsigm(float x){
    return __fdividef(1.0f, 1.0f + __expf(-x));
}
__device__ __forceinline__ u16 bfb(float x){    // f32 -> bf16 bits, RNE (inputs NaN-free)
    union { float f; uint u; } v; v.f = x;
    return (u16)((v.u + 0x7fffu + ((v.u >> 16) & 1u)) >> 16);
}
__device__ __forceinline__ f32x4 MFMA(bf16x8 a, bf16x8 b, f32x4 c){
    return __builtin_amdgcn_mfma_f32_16x16x32_bf16(a, b, c, 0, 0, 0);
}

// acc[mt][n] initialized to bias broadcast in D-layout (row = 16mt + 4*(lane>>4)+c)
__device__ __forceinline__ void ld_bias(const float* BIAS, int bb, int lane, f32x4 (&acc)[4][4]){
    #pragma unroll
    for (int mt = 0; mt < 4; ++mt){
        const f32x4 b4 = *(const f32x4*)&BIAS[bb + 16*mt + 4*(lane>>4)];
        #pragma unroll
        for (int n = 0; n < 4; ++n) acc[mt][n] = b4;
    }
}

// K=32 layer: A-frags at wbase + mt*512, B from act buffer (logical bytes 0..63, swizzled)
__device__ __forceinline__ void layer_k32(const u16* SHW, const u16* AC, int wbase, int lane,
                                          f32x4 (&acc)[4][4]){
    bf16x8 A[4];
    #pragma unroll
    for (int mt = 0; mt < 4; ++mt)
        A[mt] = *(const bf16x8*)&SHW[wbase + mt*512 + lane*8];
    #pragma unroll
    for (int n = 0; n < 4; ++n){
        const int b   = 16*n + (lane & 15);
        const int ofs = (16*(lane>>4)) ^ ((b & 7) << 4);
        const bf16x8 B = *(const bf16x8*)&AC[b*64 + (ofs >> 1)];
        #pragma unroll
        for (int mt = 0; mt < 4; ++mt) acc[mt][n] = MFMA(A[mt], B, acc[mt][n]);
    }
}

// K=64 layer: 8 A-frags, 8 B-frags, 32 MFMA
__device__ __forceinline__ void layer_k64(const u16* SHW, const u16* AC, int wbase, int lane,
                                          f32x4 (&acc)[4][4]){
    bf16x8 A[4][2];
    #pragma unroll
    for (int mt = 0; mt < 4; ++mt)
        #pragma unroll
        for (int s = 0; s < 2; ++s)
            A[mt][s] = *(const bf16x8*)&SHW[wbase + (mt*2+s)*512 + lane*8];
    #pragma unroll
    for (int n = 0; n < 4; ++n){
        const int b   = 16*n + (lane & 15);
        const int swz = (b & 7) << 4;
        #pragma unroll
        for (int s = 0; s < 2; ++s){
            const int ofs = (64*s + 16*(lane>>4)) ^ swz;
            const bf16x8 B = *(const bf16x8*)&AC[b*64 + (ofs >> 1)];
            #pragma unroll
            for (int mt = 0; mt < 4; ++mt) acc[mt][n] = MFMA(A[mt][s], B, acc[mt][n]);
        }
    }
}

// heads: single M-tile (rows 0..7 = v, row 8 = w-logit)
__device__ __forceinline__ void head_k64(const u16* SHW, const u16* AC, int lane, f32x4 (&ah)[4]){
    bf16x8 A[2];
    A[0] = *(const bf16x8*)&SHW[OF_W2AB + lane*8];
    A[1] = *(const bf16x8*)&SHW[OF_W2AB + 512 + lane*8];
    #pragma unroll
    for (int n = 0; n < 4; ++n){
        const int b   = 16*n + (lane & 15);
        const int swz = (b & 7) << 4;
        #pragma unroll
        for (int s = 0; s < 2; ++s){
            const int ofs = (64*s + 16*(lane>>4)) ^ swz;
            const bf16x8 B = *(const bf16x8*)&AC[b*64 + (ofs >> 1)];
            ah[n] = MFMA(A[s], B, ah[n]);
        }
    }
}

__device__ __forceinline__ uint2 pack4(float t0, float t1, float t2, float t3){
    uint2 r;
    r.x = (uint)bfb(t0) | ((uint)bfb(t1) << 16);
    r.y = (uint)bfb(t2) | ((uint)bfb(t3) << 16);
    return r;
}
// store 4 consecutive j at (row=b, tile mt) into swizzled act buffer
__device__ __forceinline__ void st_act(u16* AC, int lane, int mt, int n, uint2 p){
    const int b   = 16*n + (lane & 15);
    const int ofs = (32*mt + 8*(lane>>4)) ^ ((b & 7) << 4);
    *(uint2*)&AC[b*64 + (ofs >> 1)] = p;
}
__device__ __forceinline__ void epi_tanh_store(u16* AC, int lane, const f32x4 (&acc)[4][4]){
    #pragma unroll
    for (int mt = 0; mt < 4; ++mt)
        #pragma unroll
        for (int n = 0; n < 4; ++n)
            st_act(AC, lane, mt, n, pack4(ftanh(acc[mt][n][0]), ftanh(acc[mt][n][1]),
                                          ftanh(acc[mt][n][2]), ftanh(acc[mt][n][3])));
}

// lane writes its own row (b=lane): dims 0..31 as bf16, zero-padded past NR
template<int NR>
__device__ __forceinline__ void write_xrow(u16* AC, int lane, const float (&x)[NR]){
    uint buf[16];
    #pragma unroll
    for (int i = 0; i < 16; ++i){
        uint lo = (2*i   < NR) ? (uint)bfb(x[2*i])   : 0u;
        uint hi = (2*i+1 < NR) ? (uint)bfb(x[2*i+1]) : 0u;
        buf[i] = lo | (hi << 16);
    }
    const int sx = (lane & 7) << 4;
    #pragma unroll
    for (int blk = 0; blk < 4; ++blk){
        const int ofs = (16*blk) ^ sx;
        uint4 q = make_uint4(buf[4*blk], buf[4*blk+1], buf[4*blk+2], buf[4*blk+3]);
        *(uint4*)&AC[lane*64 + (ofs >> 1)] = q;
    }
}

__global__ __launch_bounds__(256, 2)
void net_mfma(const float* __restrict__ states, const float* __restrict__ action,
              const float* __restrict__ b_type, const float* __restrict__ table,
              const float* __restrict__ W1,  const float* __restrict__ b1,
              const float* __restrict__ W1b, const float* __restrict__ b1b,
              const float* __restrict__ W1c, const float* __restrict__ b1c,
              const float* __restrict__ W2a, const float* __restrict__ b2a,
              const float* __restrict__ W2b, const float* __restrict__ b2b,
              const float* __restrict__ Ta1, const float* __restrict__ ta1,
              const float* __restrict__ Ta2, const float* __restrict__ ta2,
              const float* __restrict__ Tb1, const float* __restrict__ tb1,
              const float* __restrict__ Tb2, const float* __restrict__ tb2,
              float* __restrict__ out, int Btot)
{
    __shared__ u16   SHW[WTOT];        // 46 KB weight fragments
    __shared__ float BIAS[464];        // 1.8 KB
    __shared__ u16   ACT[4*4096];      // 32 KB: per-wave [64][64] bf16, XOR-swizzled

    const int tid = threadIdx.x;

    // ---------------- weight staging ----------------
    { uint* z = (uint*)&SHW[OF_W1];    // zero pad region (K<32 matrices + W2ab)
      #pragma unroll 1
      for (int i = tid; i < 3584; i += 256) z[i] = 0u; }
    __syncthreads();
    {
        const float* Wsrc[4] = {W1b, W1c, Ta2, Tb2};
        const int    Wdst[4] = {OF_W1B, OF_W1C, OF_TA2, OF_TB2};
        #pragma unroll 1
        for (int m = 0; m < 4; ++m){
            const float* Wg = Wsrc[m]; const int bb = Wdst[m];
            #pragma unroll 1
            for (int idx = tid; idx < 4096; idx += 256){
                const int k = idx >> 6, j = idx & 63;   // A[j][k] = W[k][j]
                SHW[bb + (((j>>4)<<1)|(k>>5))*512 + ((j&15)|(((k>>3)&3)<<4))*8 + (k&7)] = bfb(Wg[idx]);
            }
        }
    }
    #pragma unroll 1
    for (int idx = tid; idx < 896; idx += 256){          // W1: 14x64
        const int k = idx >> 6, j = idx & 63;
        SHW[OF_W1 + (j>>4)*512 + ((j&15)|(((k>>3)&3)<<4))*8 + (k&7)] = bfb(W1[idx]);
    }
    #pragma unroll 1
    for (int idx = tid; idx < 320; idx += 256){          // Ta1 / Tb1: 5x64
        const int k = idx >> 6, j = idx & 63;
        const int d = (j>>4)*512 + ((j&15)|(((k>>3)&3)<<4))*8 + (k&7);
        SHW[OF_TA1 + d] = bfb(Ta1[idx]);
        SHW[OF_TB1 + d] = bfb(Tb1[idx]);
    }
    #pragma unroll 1
    for (int idx = tid; idx < 576; idx += 256){          // W2ab: m=i(0..8), k=j(0..63)
        const int j = idx / 9, i = idx - 9*j;
        const float v = (i < 8) ? W2a[j*8 + i] : W2b[j];
        SHW[OF_W2AB + (j>>5)*512 + (i|(((j>>3)&3)<<4))*8 + (j&7)] = bfb(v);
    }
    if (tid < 64){
        BIAS[BTA1+tid]=ta1[tid]; BIAS[BTA2+tid]=ta2[tid];
        BIAS[BTB1+tid]=tb1[tid]; BIAS[BTB2+tid]=tb2[tid];
        BIAS[BB1+tid]=b1[tid];   BIAS[BB1B+tid]=b1b[tid]; BIAS[BB1C+tid]=b1c[tid];
    }
    if (tid < 16) BIAS[BH+tid] = (tid < 8) ? b2a[tid] : (tid == 8 ? b2b[0] : 0.0f);
    __syncthreads();
    // ------------- no more block barriers: waves independent -------------

    const int lane = tid & 63;
    const int wv   = tid >> 6;
    u16* AC = &ACT[wv << 12];
    const int ebw   = blockIdx.x*256 + wv*64;          // wave's element base
    const int elast = Btot - 1;
    const int eme   = min(ebw + lane, elast);          // lane's own element (clamped)

    // per-lane inputs
    float a8[8];
    { const float* ap = action + (size_t)eme*8;
      const float4 a0 = *(const float4*)ap; const float4 a1 = *(const float4*)(ap+4);
      a8[0]=a0.x; a8[1]=a0.y; a8[2]=a0.z; a8[3]=a0.w; a8[4]=a1.x; a8[5]=a1.y; a8[6]=a1.z; a8[7]=a1.w; }
    const float* sp = states + (size_t)eme*54;

    // ---------------- gate1 (kept in regs, D-layout) ----------------
    f32x4 g[4][4];
    {
        float x5[5];
        { const float* bp = b_type + (size_t)eme*5;
          #pragma unroll
          for (int k = 0; k < 5; ++k) x5[k] = bp[k]; }
        write_xrow<5>(AC, lane, x5);
        f32x4 acc[4][4];
        ld_bias(BIAS, BTA1, lane, acc);
        layer_k32(SHW, AC, OF_TA1, lane, acc);
        epi_tanh_store(AC, lane, acc);
        ld_bias(BIAS, BTA2, lane, acc);
        layer_k64(SHW, AC, OF_TA2, lane, acc);
        #pragma unroll
        for (int mt = 0; mt < 4; ++mt)
            #pragma unroll
            for (int n = 0; n < 4; ++n)
                #pragma unroll
                for (int c = 0; c < 4; ++c) g[mt][n][c] = ftanh(acc[mt][n][c]);
    }

    f32x4 ro[4];
    #pragma unroll
    for (int n = 0; n < 4; ++n) ro[n] = f32x4{0.f, 0.f, 0.f, 0.f};

    // ---------------- 4 contexts: r=0..2 state rows, r=3 table ----------------
    #pragma unroll 1
    for (int r = 0; r < 4; ++r){
        const bool ht = (r < 3);
        uint2 tgp[4][4];                       // tg packed bf16x2, only if ht

        if (ht){
            float xt[5];
            #pragma unroll
            for (int k = 0; k < 5; ++k) xt[k] = sp[r*18 + 13 + k];
            write_xrow<5>(AC, lane, xt);
            f32x4 a2[4][4];
            ld_bias(BIAS, BTB1, lane, a2);
            layer_k32(SHW, AC, OF_TB1, lane, a2);
            epi_tanh_store(AC, lane, a2);
            ld_bias(BIAS, BTB2, lane, a2);
            layer_k64(SHW, AC, OF_TB2, lane, a2);
            #pragma unroll
            for (int mt = 0; mt < 4; ++mt)
                #pragma unroll
                for (int n = 0; n < 4; ++n)
                    tgp[mt][n] = pack4(ftanh(a2[mt][n][0]), ftanh(a2[mt][n][1]),
                                       ftanh(a2[mt][n][2]), ftanh(a2[mt][n][3]));
        }

        // x14 = [rel(8), st(6) or table(6)]
        float x14[14];
        #pragma unroll
        for (int k = 0; k < 8; ++k) x14[k] = a8[k];
        if (ht){
            x14[0] -= sp[r*18 + 0];
            x14[1] -= sp[r*18 + 1];
            #pragma unroll
            for (int k = 0; k < 6; ++k) x14[8 + k] = sp[r*18 + 3 + k];
        } else {
            const float* tp = table + (size_t)eme*6;
            #pragma unroll
            for (int k = 0; k < 6; ++k) x14[8 + k] = tp[k];
        }
        write_xrow<14>(AC, lane, x14);

        f32x4 acc[4][4];
        ld_bias(BIAS, BB1, lane, acc);
        layer_k32(SHW, AC, OF_W1, lane, acc);
        epi_tanh_store(AC, lane, acc);

        ld_bias(BIAS, BB1B, lane, acc);
        layer_k64(SHW, AC, OF_W1B, lane, acc);
        #pragma unroll
        for (int mt = 0; mt < 4; ++mt)                       // tanh * gate1
            #pragma unroll
            for (int n = 0; n < 4; ++n)
                st_act(AC, lane, mt, n,
                       pack4(ftanh(acc[mt][n][0])*g[mt][n][0], ftanh(acc[mt][n][1])*g[mt][n][1],
                             ftanh(acc[mt][n][2])*g[mt][n][2], ftanh(acc[mt][n][3])*g[mt][n][3]));

        ld_bias(BIAS, BB1C, lane, acc);
        layer_k64(SHW, AC, OF_W1C, lane, acc);
        #pragma unroll
        for (int mt = 0; mt < 4; ++mt){                      // tanh (* tg)
            #pragma unroll
            for (int n = 0; n < 4; ++n){
                float t0 = ftanh(acc[mt][n][0]), t1 = ftanh(acc[mt][n][1]);
                float t2 = ftanh(acc[mt][n][2]), t3 = ftanh(acc[mt][n][3]);
                if (ht){
                    const uint lo = tgp[mt][n].x, hi = tgp[mt][n].y;
                    t0 *= __uint_as_float(lo << 16);
                    t1 *= __uint_as_float(lo & 0xffff0000u);
                    t2 *= __uint_as_float(hi << 16);
                    t3 *= __uint_as_float(hi & 0xffff0000u);
                }
                st_act(AC, lane, mt, n, pack4(t0, t1, t2, t3));
            }
        }

        // heads: rows 0..7 = v, row 8 = w-logit
        f32x4 ah[4];
        { const f32x4 b4 = *(const f32x4*)&BIAS[BH + 4*(lane>>4)];
          #pragma unroll
          for (int n = 0; n < 4; ++n) ah[n] = b4; }
        head_k64(SHW, AC, lane, ah);

        #pragma unroll
        for (int n = 0; n < 4; ++n){
            float wm = fsigm(ah[n][0]);                      // meaningful on lanes 32..47
            if (ht){
                const int e2 = min(ebw + 16*n + (lane & 15), elast);
                const float st0 = states[(size_t)e2*54 + r*18 + 3];
                wm = (st0 == -1.0f) ? 0.0f : wm;
            }
            const float w = __shfl(wm, 32 + (lane & 15), 64);
            #pragma unroll
            for (int c = 0; c < 4; ++c) ro[n][c] += w * ah[n][c];
        }
    }

    // ---------------- out = action + residuals ----------------
    if (lane < 32){
        #pragma unroll
        for (int n = 0; n < 4; ++n){
            const int e2 = ebw + 16*n + (lane & 15);
            if (e2 < Btot){
                const int co = 4*(lane >> 4);
                const float4 av = *(const float4*)(action + (size_t)e2*8 + co);
                float4 res;
                res.x = av.x + ro[n][0]; res.y = av.y + ro[n][1];
                res.z = av.z + ro[n][2]; res.w = av.w + ro[n][3];
                *(float4*)(out + (size_t)e2*8 + co) = res;
            }
        }
    }
}

extern "C" void kernel_launch(void* const* d_in, const int* in_sizes, int n_in,
                              void* d_out, int out_size, void* d_ws, size_t ws_size,
                              hipStream_t stream)
{
    const float* states = (const float*)d_in[0];
    const float* action = (const float*)d_in[1];
    const float* b_type = (const float*)d_in[2];
    const float* table  = (const float*)d_in[3];
    const float* W1  = (const float*)d_in[4];
    const float* b1  = (const float*)d_in[5];
    const float* W1b = (const float*)d_in[6];
    const float* b1b = (const float*)d_in[7];
    const float* W1c = (const float*)d_in[8];
    const float* b1c = (const float*)d_in[9];
    const float* W2a = (const float*)d_in[10];
    const float* b2a = (const float*)d_in[11];
    const float* W2b = (const float*)d_in[12];
    const float* b2b = (const float*)d_in[13];
    const float* Ta1 = (const float*)d_in[14];
    const float* ta1 = (const float*)d_in[15];
    const float* Ta2 = (const float*)d_in[16];
    const float* ta2 = (const float*)d_in[17];
    const float* Tb1 = (const float*)d_in[18];
    const float* tb1 = (const float*)d_in[19];
    const float* Tb2 = (const float*)d_in[20];
    const float* tb2 = (const float*)d_in[21];
    float* out = (float*)d_out;

    const int Btot = in_sizes[1] / 8;                  // action is (B, 8)
    const int grid = (Btot + 255) / 256;               // 256 threads = 4 waves, 64 elem/wave
    net_mfma<<<dim3(grid), dim3(256), 0, stream>>>(
        states, action, b_type, table,
        W1, b1, W1b, b1b, W1c, b1c, W2a, b2a, W2b, b2b,
        Ta1, ta1, Ta2, ta2, Tb1, tb1, Tb2, tb2,
        out, Btot);
}

// Round 3
// 122.243 us; speedup vs baseline: 8.1124x; 2.2101x over previous
//
#include <hip/hip_runtime.h>

typedef unsigned int  uint;
typedef unsigned short u16;
typedef __attribute__((ext_vector_type(8))) short bf16x8;   // 8 bf16 in 4 VGPRs
typedef __attribute__((ext_vector_type(4))) float f32x4;

// ---- LDS weight-fragment offsets (u16 units) ----
#define OF_W1B   0
#define OF_W1C   4096
#define OF_TA2   8192
#define OF_TB2   12288
#define OF_W1    16384
#define OF_TA1   18432
#define OF_TB1   20480
#define OF_W2AB  22528
#define WTOT     23552
// ---- bias offsets (f32 units); K=32 layers use the bias-in-k31 trick instead ----
#define BTA2 0
#define BTB2 64
#define BB1B 128
#define BB1C 192
#define BH   256   // [0..7]=b2a, [8]=b2b, [9..15]=0
#define BIASN 272

#if defined(__has_builtin) && __has_builtin(__builtin_amdgcn_exp2f)
#define EXP2F(x) __builtin_amdgcn_exp2f(x)
#else
#define EXP2F(x) __expf((x) * 0.6931471805599453f)
#endif
#if defined(__has_builtin) && __has_builtin(__builtin_amdgcn_rcpf)
#define RCPF(x) __builtin_amdgcn_rcpf(x)
#else
#define RCPF(x) __fdividef(1.0f, (x))
#endif

// tanh = 1 - 2/(exp2(x*2*log2e)+1): mul, exp2, add, rcp, fma (2 trans, 3 VALU)
__device__ __forceinline__ float ftanh(float x){
    const float e = EXP2F(x * 2.8853900817779268f);
    return __builtin_fmaf(-2.0f, RCPF(e + 1.0f), 1.0f);
}
__device__ __forceinline__ float fsigm(float x){
    return RCPF(1.0f + EXP2F(-1.4426950408889634f * x));
}
// pack 2 f32 -> 2 bf16 (RNE), 1 instruction
__device__ __forceinline__ uint cvtpk(float lo, float hi){
    uint r; asm("v_cvt_pk_bf16_f32 %0, %1, %2" : "=v"(r) : "v"(lo), "v"(hi)); return r;
}
__device__ __forceinline__ u16 bfb(float x){    // staging-only scalar pack
    union { float f; uint u; } v; v.f = x;
    return (u16)((v.u + 0x7fffu + ((v.u >> 16) & 1u)) >> 16);
}
__device__ __forceinline__ f32x4 MFMA(bf16x8 a, bf16x8 b, f32x4 c){
    return __builtin_amdgcn_mfma_f32_16x16x32_bf16(a, b, c, 0, 0, 0);
}

__device__ __forceinline__ void zacc(f32x4 (&acc)[4][4]){
    #pragma unroll
    for (int mt = 0; mt < 4; ++mt)
        #pragma unroll
        for (int n = 0; n < 4; ++n) acc[mt][n] = f32x4{0.f, 0.f, 0.f, 0.f};
}
__device__ __forceinline__ void ld_bias(const float* BIAS, int bb, int q, f32x4 (&acc)[4][4]){
    #pragma unroll
    for (int mt = 0; mt < 4; ++mt){
        const f32x4 b4 = *(const f32x4*)&BIAS[bb + 16*mt + 4*q];
        #pragma unroll
        for (int n = 0; n < 4; ++n) acc[mt][n] = b4;
    }
}

// ---- layers: Ab = &SHW[lane*8], Bb = &ACT_wave[lane*8]; all offsets immediate ----
__device__ __forceinline__ void layer_k32(const u16* Ab, const u16* Bb, int WB, f32x4 (&acc)[4][4]){
    bf16x8 A[4];
    #pragma unroll
    for (int mt = 0; mt < 4; ++mt) A[mt] = *(const bf16x8*)&Ab[WB + mt*512];
    #pragma unroll
    for (int n = 0; n < 4; ++n){
        const bf16x8 B = *(const bf16x8*)&Bb[n*1024];
        #pragma unroll
        for (int mt = 0; mt < 4; ++mt) acc[mt][n] = MFMA(A[mt], B, acc[mt][n]);
    }
}
__device__ __forceinline__ void layer_k64(const u16* Ab, const u16* Bb, int WB, f32x4 (&acc)[4][4]){
    #pragma unroll
    for (int s = 0; s < 2; ++s){          // s-outer: only 4 A-frags (16 VGPR) live
        bf16x8 A[4];
        #pragma unroll
        for (int mt = 0; mt < 4; ++mt) A[mt] = *(const bf16x8*)&Ab[WB + (mt*2+s)*512];
        #pragma unroll
        for (int n = 0; n < 4; ++n){
            const bf16x8 B = *(const bf16x8*)&Bb[n*1024 + s*512];
            #pragma unroll
            for (int mt = 0; mt < 4; ++mt) acc[mt][n] = MFMA(A[mt], B, acc[mt][n]);
        }
    }
}
__device__ __forceinline__ void head_k64(const u16* Ab, const u16* Bb, f32x4 (&ah)[4]){
    const bf16x8 A0 = *(const bf16x8*)&Ab[OF_W2AB];
    const bf16x8 A1 = *(const bf16x8*)&Ab[OF_W2AB + 512];
    #pragma unroll
    for (int n = 0; n < 4; ++n){
        const bf16x8 B0 = *(const bf16x8*)&Bb[n*1024];
        const bf16x8 B1 = *(const bf16x8*)&Bb[n*1024 + 512];
        ah[n] = MFMA(A0, B0, ah[n]);
        ah[n] = MFMA(A1, B1, ah[n]);
    }
}

// D-epilogue store: lane holds rows j=16mt+4q+c of col b=16n+(lane&15); dest = B-frag slot
// EW = &ACT_wave[(q>>1)*128 + (lane&15)*8 + 4*(q&1)]
__device__ __forceinline__ void stD(u16* EW, int mt, int n, uint lo, uint hi){
    *(uint2*)&EW[(n*2 + (mt>>1))*512 + (mt&1)*256] = make_uint2(lo, hi);
}
__device__ __forceinline__ void epi_tanh(u16* EW, const f32x4 (&acc)[4][4]){
    #pragma unroll
    for (int mt = 0; mt < 4; ++mt)
        #pragma unroll
        for (int n = 0; n < 4; ++n)
            stD(EW, mt, n, cvtpk(ftanh(acc[mt][n][0]), ftanh(acc[mt][n][1])),
                           cvtpk(ftanh(acc[mt][n][2]), ftanh(acc[mt][n][3])));
}

// input row write: lane's own row, k=0..31 (k31 = 1.0 -> bias row multiplier)
// XW = &ACT_wave[(lane>>4)*1024 + (lane&15)*8]
template<int NR>
__device__ __forceinline__ void write_xrow(u16* XW, const float (&x)[NR]){
    uint buf[16];
    #pragma unroll
    for (int i = 0; i < 16; ++i){
        if (2*i < NR){
            const float lo = x[2*i];
            const float hi = (2*i+1 < NR) ? x[2*i+1] : 0.f;
            buf[i] = cvtpk(lo, hi);
        } else buf[i] = 0u;
    }
    buf[15] = 0x3F800000u;   // k30=0, k31=bf16(1.0)
    #pragma unroll
    for (int kb = 0; kb < 4; ++kb)
        *(uint4*)&XW[kb*128] = make_uint4(buf[4*kb], buf[4*kb+1], buf[4*kb+2], buf[4*kb+3]);
}

__device__ __forceinline__ void stage_w64(u16* SHW, const float* __restrict__ Wg, int bb, int tid){
    #pragma unroll 1
    for (int idx = tid; idx < 4096; idx += 256){
        const int k = idx >> 6, j = idx & 63;   // A[j][k] = W[k][j]
        SHW[bb + (((j>>4)<<1)|(k>>5))*512 + ((j&15)|(((k>>3)&3)<<4))*8 + (k&7)] = bfb(Wg[idx]);
    }
}

__global__ __launch_bounds__(256)
__attribute__((amdgpu_waves_per_eu(2, 2)))   // LDS caps at 2 blocks/CU anyway; allow 256 VGPR
void net_mfma(const float* __restrict__ states, const float* __restrict__ action,
              const float* __restrict__ b_type, const float* __restrict__ table,
              const float* __restrict__ W1,  const float* __restrict__ b1,
              const float* __restrict__ W1b, const float* __restrict__ b1b,
              const float* __restrict__ W1c, const float* __restrict__ b1c,
              const float* __restrict__ W2a, const float* __restrict__ b2a,
              const float* __restrict__ W2b, const float* __restrict__ b2b,
              const float* __restrict__ Ta1, const float* __restrict__ ta1,
              const float* __restrict__ Ta2, const float* __restrict__ ta2,
              const float* __restrict__ Tb1, const float* __restrict__ tb1,
              const float* __restrict__ Tb2, const float* __restrict__ tb2,
              float* __restrict__ out, int Btot)
{
    __shared__ u16   SHW[WTOT];        // 46 KB weight fragments (block-shared)
    __shared__ float BIAS[BIASN];
    __shared__ u16   ACT[4*4096];      // 32 KB: per-wave [tile n][sub s][lane][8] bf16

    const int tid = threadIdx.x;

    // ---------------- weight staging ----------------
    { uint* z = (uint*)&SHW[OF_W1];
      #pragma unroll 1
      for (int i = tid; i < 3584; i += 256) z[i] = 0u; }
    __syncthreads();
    stage_w64(SHW, W1b, OF_W1B, tid);
    stage_w64(SHW, W1c, OF_W1C, tid);
    stage_w64(SHW, Ta2, OF_TA2, tid);
    stage_w64(SHW, Tb2, OF_TB2, tid);
    #pragma unroll 1
    for (int idx = tid; idx < 896; idx += 256){          // W1: 14x64
        const int k = idx >> 6, j = idx & 63;
        SHW[OF_W1 + (j>>4)*512 + ((j&15)|(((k>>3)&3)<<4))*8 + (k&7)] = bfb(W1[idx]);
    }
    #pragma unroll 1
    for (int idx = tid; idx < 320; idx += 256){          // Ta1 / Tb1: 5x64
        const int k = idx >> 6, j = idx & 63;
        const int d = (j>>4)*512 + ((j&15)|(((k>>3)&3)<<4))*8 + (k&7);
        SHW[OF_TA1 + d] = bfb(Ta1[idx]);
        SHW[OF_TB1 + d] = bfb(Tb1[idx]);
    }
    #pragma unroll 1
    for (int idx = tid; idx < 512; idx += 256){          // W2a: m=i(0..7), k=j
        const int j = idx >> 3, i = idx & 7;
        SHW[OF_W2AB + (j>>5)*512 + (i|(((j>>3)&3)<<4))*8 + (j&7)] = bfb(W2a[idx]);
    }
    if (tid < 64){
        const int j = tid;
        SHW[OF_W2AB + (j>>5)*512 + (8|(((j>>3)&3)<<4))*8 + (j&7)] = bfb(W2b[j]); // m=8
        // bias-in-k31 rows for the K=32 layers
        const int d31 = ((j&15)|(3<<4))*8 + 7;
        SHW[OF_W1  + (j>>4)*512 + d31] = bfb(b1[j]);
        SHW[OF_TA1 + (j>>4)*512 + d31] = bfb(ta1[j]);
        SHW[OF_TB1 + (j>>4)*512 + d31] = bfb(tb1[j]);
        BIAS[BTA2+j] = ta2[j]; BIAS[BTB2+j] = tb2[j];
        BIAS[BB1B+j] = b1b[j]; BIAS[BB1C+j] = b1c[j];
    }
    if (tid < 16) BIAS[BH+tid] = (tid < 8) ? b2a[tid] : (tid == 8 ? b2b[0] : 0.0f);
    __syncthreads();
    // ------------- waves independent from here -------------

    const int lane = tid & 63;
    const int q    = lane >> 4;
    const int wv   = tid >> 6;
    u16* ACW = &ACT[wv << 12];
    const u16* Ab = &SHW[lane*8];
    const u16* Bb = &ACW[lane*8];
    u16* XW = &ACW[(lane>>4)*1024 + (lane&15)*8];
    u16* EW = &ACW[(q>>1)*128 + (lane&15)*8 + 4*(q&1)];

    const int ebw   = blockIdx.x*256 + wv*64;
    const int elast = Btot - 1;
    const int eme   = min(ebw + lane, elast);

    float a8[8];
    { const float* ap = action + (size_t)eme*8;
      const float4 a0 = *(const float4*)ap; const float4 a1 = *(const float4*)(ap+4);
      a8[0]=a0.x; a8[1]=a0.y; a8[2]=a0.z; a8[3]=a0.w; a8[4]=a1.x; a8[5]=a1.y; a8[6]=a1.z; a8[7]=a1.w; }
    const float* sp = states + (size_t)eme*54;

    // ---------------- gate1, packed bf16 in regs ----------------
    uint2 gp[4][4];
    {
        float x5[5];
        { const float* bp = b_type + (size_t)eme*5;
          #pragma unroll
          for (int k = 0; k < 5; ++k) x5[k] = bp[k]; }
        write_xrow<5>(XW, x5);
        f32x4 acc[4][4];
        zacc(acc);
        layer_k32(Ab, Bb, OF_TA1, acc);
        epi_tanh(EW, acc);
        ld_bias(BIAS, BTA2, q, acc);
        layer_k64(Ab, Bb, OF_TA2, acc);
        #pragma unroll
        for (int mt = 0; mt < 4; ++mt)
            #pragma unroll
            for (int n = 0; n < 4; ++n)
                gp[mt][n] = make_uint2(cvtpk(ftanh(acc[mt][n][0]), ftanh(acc[mt][n][1])),
                                       cvtpk(ftanh(acc[mt][n][2]), ftanh(acc[mt][n][3])));
    }

    f32x4 ro[4];
    #pragma unroll
    for (int n = 0; n < 4; ++n) ro[n] = f32x4{0.f, 0.f, 0.f, 0.f};

    // ---------------- 4 contexts ----------------
    #pragma unroll 1
    for (int r = 0; r < 4; ++r){
        const bool ht = (r < 3);
        uint2 tgp[4][4];
        f32x4 acc[4][4];

        if (ht){
            float xt[5];
            #pragma unroll
            for (int k = 0; k < 5; ++k) xt[k] = sp[r*18 + 13 + k];
            write_xrow<5>(XW, xt);
            zacc(acc);
            layer_k32(Ab, Bb, OF_TB1, acc);
            epi_tanh(EW, acc);
            ld_bias(BIAS, BTB2, q, acc);
            layer_k64(Ab, Bb, OF_TB2, acc);
            #pragma unroll
            for (int mt = 0; mt < 4; ++mt)
                #pragma unroll
                for (int n = 0; n < 4; ++n)
                    tgp[mt][n] = make_uint2(cvtpk(ftanh(acc[mt][n][0]), ftanh(acc[mt][n][1])),
                                            cvtpk(ftanh(acc[mt][n][2]), ftanh(acc[mt][n][3])));
        }

        float x14[14]; float maskf = 1.0f;
        #pragma unroll
        for (int k = 0; k < 8; ++k) x14[k] = a8[k];
        if (ht){
            x14[0] -= sp[r*18 + 0];
            x14[1] -= sp[r*18 + 1];
            #pragma unroll
            for (int k = 0; k < 6; ++k) x14[8 + k] = sp[r*18 + 3 + k];
            maskf = (x14[8] == -1.0f) ? 0.0f : 1.0f;
        } else {
            const float* tp = table + (size_t)eme*6;
            #pragma unroll
            for (int k = 0; k < 6; ++k) x14[8 + k] = tp[k];
        }
        write_xrow<14>(XW, x14);

        zacc(acc);
        layer_k32(Ab, Bb, OF_W1, acc);
        epi_tanh(EW, acc);

        ld_bias(BIAS, BB1B, q, acc);
        layer_k64(Ab, Bb, OF_W1B, acc);
        #pragma unroll
        for (int mt = 0; mt < 4; ++mt)                      // tanh * gate1
            #pragma unroll
            for (int n = 0; n < 4; ++n){
                const uint lo = gp[mt][n].x, hi = gp[mt][n].y;
                const float t0 = ftanh(acc[mt][n][0]) * __uint_as_float(lo << 16);
                const float t1 = ftanh(acc[mt][n][1]) * __uint_as_float(lo & 0xffff0000u);
                const float t2 = ftanh(acc[mt][n][2]) * __uint_as_float(hi << 16);
                const float t3 = ftanh(acc[mt][n][3]) * __uint_as_float(hi & 0xffff0000u);
                stD(EW, mt, n, cvtpk(t0, t1), cvtpk(t2, t3));
            }

        ld_bias(BIAS, BB1C, q, acc);
        layer_k64(Ab, Bb, OF_W1C, acc);
        #pragma unroll
        for (int mt = 0; mt < 4; ++mt)                      // tanh (* tg)
            #pragma unroll
            for (int n = 0; n < 4; ++n){
                float m0 = 1.f, m1 = 1.f, m2 = 1.f, m3 = 1.f;
                if (ht){
                    const uint lo = tgp[mt][n].x, hi = tgp[mt][n].y;
                    m0 = __uint_as_float(lo << 16); m1 = __uint_as_float(lo & 0xffff0000u);
                    m2 = __uint_as_float(hi << 16); m3 = __uint_as_float(hi & 0xffff0000u);
                }
                stD(EW, mt, n, cvtpk(ftanh(acc[mt][n][0])*m0, ftanh(acc[mt][n][1])*m1),
                               cvtpk(ftanh(acc[mt][n][2])*m2, ftanh(acc[mt][n][3])*m3));
            }

        // heads: rows 0..7 = v, row 8 = w-logit
        f32x4 ah[4];
        { const f32x4 b4 = *(const f32x4*)&BIAS[BH + 4*q];
          #pragma unroll
          for (int n = 0; n < 4; ++n) ah[n] = b4; }
        head_k64(Ab, Bb, ah);

        #pragma unroll
        for (int n = 0; n < 4; ++n){
            const float wm = fsigm(ah[n][0]);               // valid on lanes 32..47 (row 8)
            const float w  = __shfl(wm, 32 + (lane & 15), 64)
                           * __shfl(maskf, 16*n + (lane & 15), 64);
            #pragma unroll
            for (int c = 0; c < 4; ++c) ro[n][c] += w * ah[n][c];
        }
    }

    // ---------------- out = action + residuals ----------------
    if (lane < 32){
        #pragma unroll
        for (int n = 0; n < 4; ++n){
            const int e2 = ebw + 16*n + (lane & 15);
            if (e2 < Btot){
                const int co = 4*q;
                const float4 av = *(const float4*)(action + (size_t)e2*8 + co);
                float4 res;
                res.x = av.x + ro[n][0]; res.y = av.y + ro[n][1];
                res.z = av.z + ro[n][2]; res.w = av.w + ro[n][3];
                *(float4*)(out + (size_t)e2*8 + co) = res;
            }
        }
    }
}

extern "C" void kernel_launch(void* const* d_in, const int* in_sizes, int n_in,
                              void* d_out, int out_size, void* d_ws, size_t ws_size,
                              hipStream_t stream)
{
    const float* states = (const float*)d_in[0];
    const float* action = (const float*)d_in[1];
    const float* b_type = (const float*)d_in[2];
    const float* table  = (const float*)d_in[3];
    const float* W1  = (const float*)d_in[4];
    const float* b1  = (const float*)d_in[5];
    const float* W1b = (const float*)d_in[6];
    const float* b1b = (const float*)d_in[7];
    const float* W1c = (const float*)d_in[8];
    const float* b1c = (const float*)d_in[9];
    const float* W2a = (const float*)d_in[10];
    const float* b2a = (const float*)d_in[11];
    const float* W2b = (const float*)d_in[12];
    const float* b2b = (const float*)d_in[13];
    const float* Ta1 = (const float*)d_in[14];
    const float* ta1 = (const float*)d_in[15];
    const float* Ta2 = (const float*)d_in[16];
    const float* ta2 = (const float*)d_in[17];
    const float* Tb1 = (const float*)d_in[18];
    const float* tb1 = (const float*)d_in[19];
    const float* Tb2 = (const float*)d_in[20];
    const float* tb2 = (const float*)d_in[21];
    float* out = (float*)d_out;

    const int Btot = in_sizes[1] / 8;                  // action is (B, 8)
    const int grid = (Btot + 255) / 256;               // 4 waves/block, 64 elem/wave
    net_mfma<<<dim3(grid), dim3(256), 0, stream>>>(
        states, action, b_type, table,
        W1, b1, W1b, b1b, W1c, b1c, W2a, b2a, W2b, b2b,
        Ta1, ta1, Ta2, ta2, Tb1, tb1, Tb2, tb2,
        out, Btot);
}